// Round 1
// baseline (175.960 us; speedup 1.0000x reference)
//
#include <hip/hip_runtime.h>
#include <math.h>

// Self-attention: B=4, S=2048, E=1024, D=512, fp32 in/out, bf16 MFMA internally.
// Pipeline: convert -> fused QKV GEMM -> V transpose -> causal scores GEMM ->
//           row softmax (in-place P, zero-filled above diag) -> causal PV GEMM.

typedef __attribute__((ext_vector_type(4))) float f32x4;
typedef __attribute__((ext_vector_type(8))) short bf16x8;     // 8 bf16 (4 VGPRs) MFMA frag
typedef __attribute__((ext_vector_type(8))) unsigned short u16x8;

#define B_ 4
#define S_ 2048
#define E_ 1024
#define D_ 512
#define M_ (B_*S_)   // 8192
#define N3_ (3*D_)   // 1536
#define LT (128*64)  // LDS tile: 128 rows x 64 bf16

__device__ __forceinline__ unsigned short f2bf(float f) {
  unsigned u = __float_as_uint(f);
  u += 0x7fffu + ((u >> 16) & 1u);   // round-to-nearest-even
  return (unsigned short)(u >> 16);
}

__device__ __forceinline__ float bf2f(unsigned short h) {
  return __uint_as_float(((unsigned)h) << 16);
}

// ---- GEMM core: 128x128 tile, BK=64, 4 waves (2x2), 16x16x32 bf16 MFMA ----

__device__ __forceinline__ void stage_tile(const unsigned short* __restrict__ g, long ld,
                                           long rowBase, int kBase,
                                           unsigned short* lds, int wave, int lane) {
  // stage a 128x64 bf16 tile, linear LDS layout [row][64], via global_load_lds w16.
  // lane l of a wave writes bytes [l*16, l*16+16) at the wave-uniform LDS base:
  // row = i*8 + (l>>3), col8 = (l&7)*8  ->  linear offset 16*l bytes. Matches HW.
  const unsigned short* gp = g + (rowBase + wave*32 + (lane>>3))*ld + kBase + (lane&7)*8;
  unsigned short* lp = lds + wave*32*64;
  #pragma unroll
  for (int i = 0; i < 4; ++i) {
    __builtin_amdgcn_global_load_lds(
      (const __attribute__((address_space(1))) void*)(gp + (long)i*8*ld),
      (__attribute__((address_space(3))) void*)(lp + i*8*64),
      16, 0, 0);
  }
}

__device__ __forceinline__ void compute_tile(const unsigned short* As, const unsigned short* Bs,
                                             int wm, int wn, int lane, f32x4 acc[4][4]) {
  int lm = lane & 15;
  int lk = (lane >> 4) * 8;
  #pragma unroll
  for (int kk = 0; kk < 2; ++kk) {
    bf16x8 af[4], bf[4];
    #pragma unroll
    for (int mt = 0; mt < 4; ++mt)
      af[mt] = *(const bf16x8*)(As + (wm*64 + mt*16 + lm)*64 + kk*32 + lk);
    #pragma unroll
    for (int nt = 0; nt < 4; ++nt)
      bf[nt] = *(const bf16x8*)(Bs + (wn*64 + nt*16 + lm)*64 + kk*32 + lk);
    #pragma unroll
    for (int mt = 0; mt < 4; ++mt)
      #pragma unroll
      for (int nt = 0; nt < 4; ++nt)
        acc[mt][nt] = __builtin_amdgcn_mfma_f32_16x16x32_bf16(af[mt], bf[nt], acc[mt][nt], 0, 0, 0);
  }
}

__device__ __forceinline__ void gemm_mainloop(
    const unsigned short* __restrict__ A, long lda, long rowA,
    const unsigned short* __restrict__ Bt, long ldb, long rowB,
    int nsteps,
    unsigned short (*As)[LT], unsigned short (*Bs)[LT],
    int wave, int lane, int wm, int wn, f32x4 acc[4][4]) {
  // T3-minimum 2-phase double-buffered loop; __syncthreads drains vmcnt+lgkm.
  stage_tile(A, lda, rowA, 0, As[0], wave, lane);
  stage_tile(Bt, ldb, rowB, 0, Bs[0], wave, lane);
  __syncthreads();
  int cur = 0;
  for (int kt = 1; kt < nsteps; ++kt) {
    stage_tile(A, lda, rowA, kt*64, As[cur^1], wave, lane);
    stage_tile(Bt, ldb, rowB, kt*64, Bs[cur^1], wave, lane);
    compute_tile(As[cur], Bs[cur], wm, wn, lane, acc);
    __syncthreads();
    cur ^= 1;
  }
  compute_tile(As[cur], Bs[cur], wm, wn, lane, acc);
}

// ---- kernels ----

__global__ __launch_bounds__(256) void convert_f32_bf16(const float* __restrict__ src,
                                                        unsigned short* __restrict__ dst) {
  long i = (long)blockIdx.x*256 + threadIdx.x;  // 8 elems per thread
  f32x4 a = ((const f32x4*)src)[2*i];
  f32x4 b = ((const f32x4*)src)[2*i + 1];
  u16x8 o;
  #pragma unroll
  for (int j = 0; j < 4; ++j) { o[j] = f2bf(a[j]); o[4+j] = f2bf(b[j]); }
  ((u16x8*)dst)[i] = o;
}

// wbT[n][k] = w_sel[k][n&511], n in [0,1536). Column reads hit L2/L3 (6 MB total).
__global__ __launch_bounds__(256) void build_wT(const float* __restrict__ wq,
                                                const float* __restrict__ wk,
                                                const float* __restrict__ wv,
                                                unsigned short* __restrict__ wbT) {
  int o = blockIdx.x*256 + threadIdx.x;   // 1,572,864 total
  int n = o >> 10, k = o & 1023;
  const float* w = (n < 512) ? wq : ((n < 1024) ? wk : wv);
  int d = n & 511;
  wbT[o] = f2bf(w[(long)k*512 + d]);
}

__global__ __launch_bounds__(256) void qkv_gemm(
    const unsigned short* __restrict__ xb, const unsigned short* __restrict__ wbT,
    const float* __restrict__ bq, const float* __restrict__ bk, const float* __restrict__ bv,
    unsigned short* __restrict__ qb, unsigned short* __restrict__ kb,
    unsigned short* __restrict__ vb) {
  __shared__ unsigned short As[2][LT], Bs[2][LT];
  int tid = threadIdx.x, wave = tid >> 6, lane = tid & 63;
  int wm = wave >> 1, wn = wave & 1;
  long rowA = (long)blockIdx.y * 128;   // m block (8192/128 = 64)
  long rowB = (long)blockIdx.x * 128;   // n block (1536/128 = 12)
  f32x4 acc[4][4] = {};
  gemm_mainloop(xb, E_, rowA, wbT, E_, rowB, E_/64, As, Bs, wave, lane, wm, wn, acc);
  int lr = (lane >> 4) * 4, lc = lane & 15;
  #pragma unroll
  for (int nt = 0; nt < 4; ++nt) {
    int n = (int)rowB + wn*64 + nt*16 + lc;
    int d = n & 511;
    float bias; unsigned short* dst;
    if (n < 512)       { bias = bq[d]; dst = qb; }
    else if (n < 1024) { bias = bk[d]; dst = kb; }
    else               { bias = bv[d]; dst = vb; }
    #pragma unroll
    for (int mt = 0; mt < 4; ++mt) {
      #pragma unroll
      for (int j = 0; j < 4; ++j) {
        long m = rowA + wm*64 + mt*16 + lr + j;
        dst[m*D_ + d] = f2bf(acc[mt][nt][j] + bias);
      }
    }
  }
}

__global__ __launch_bounds__(256) void transpose_v(const unsigned short* __restrict__ vb,
                                                   unsigned short* __restrict__ vtb) {
  int dblk = blockIdx.x;   // 0..7
  int sblk = blockIdx.y;   // 0..31
  int b = blockIdx.z;
  __shared__ unsigned short ls[64][72];  // pad 8 keeps 16B alignment, breaks conflicts
  int tid = threadIdx.x;
  int r = tid >> 3, c8 = (tid & 7) * 8;
  long d0 = (long)dblk*64, s0 = (long)sblk*64;
  #pragma unroll
  for (int p = 0; p < 2; ++p) {
    u16x8 v = *(const u16x8*)(vb + ((long)b*S_ + s0 + r + p*32)*D_ + d0 + c8);
    *(u16x8*)&ls[r + p*32][c8] = v;
  }
  __syncthreads();
  #pragma unroll
  for (int p = 0; p < 2; ++p) {
    int d = r + p*32;
    u16x8 o;
    #pragma unroll
    for (int j = 0; j < 8; ++j) o[j] = ls[c8 + j][d];
    *(u16x8*)(vtb + ((long)b*D_ + d0 + d)*S_ + s0 + c8) = o;
  }
}

__global__ __launch_bounds__(256) void scores_gemm(
    const unsigned short* __restrict__ qb, const unsigned short* __restrict__ kb,
    unsigned short* __restrict__ sc) {
  int jb = blockIdx.x, ib = blockIdx.y, b = blockIdx.z;
  if (jb > ib) return;   // strictly-above-diagonal blocks never read downstream
  __shared__ unsigned short As[2][LT], Bs[2][LT];
  int tid = threadIdx.x, wave = tid >> 6, lane = tid & 63;
  int wm = wave >> 1, wn = wave & 1;
  const unsigned short* A  = qb + (long)b*S_*D_;
  const unsigned short* Bt = kb + (long)b*S_*D_;   // k stored [s][d] == [n][k]
  long rowA = (long)ib*128, rowB = (long)jb*128;
  f32x4 acc[4][4] = {};
  gemm_mainloop(A, D_, rowA, Bt, D_, rowB, D_/64, As, Bs, wave, lane, wm, wn, acc);
  unsigned short* so = sc + (long)b*S_*S_;
  int lr = (lane >> 4) * 4, lc = lane & 15;
  #pragma unroll
  for (int mt = 0; mt < 4; ++mt)
    #pragma unroll
    for (int nt = 0; nt < 4; ++nt)
      #pragma unroll
      for (int j = 0; j < 4; ++j) {
        long m = rowA + wm*64 + mt*16 + lr + j;
        long n = rowB + wn*64 + nt*16 + lc;
        so[m*S_ + n] = f2bf(acc[mt][nt][j]);   // raw score; scale+mask in softmax
      }
}

// one block per row; reads bf16 scores cols 0..r, writes P bf16 over all 2048 cols
// (zeros where masked) -> PV never multiplies garbage.
__global__ __launch_bounds__(256) void softmax_rows(unsigned short* __restrict__ sc) {
  int r = blockIdx.x, b = blockIdx.y;
  unsigned short* row = sc + ((long)b*S_ + r)*S_;
  int tid = threadIdx.x;
  u16x8 uv = *(const u16x8*)(row + tid*8);
  int j0 = tid * 8;
  float s[8];
  #pragma unroll
  for (int j = 0; j < 8; ++j) s[j] = (j0 + j <= r) ? bf2f(uv[j]) : -INFINITY;
  float mx = s[0];
  #pragma unroll
  for (int j = 1; j < 8; ++j) mx = fmaxf(mx, s[j]);
  #pragma unroll
  for (int o = 32; o > 0; o >>= 1) mx = fmaxf(mx, __shfl_xor(mx, o));
  __shared__ float red[4];
  int wave = tid >> 6, lane = tid & 63;
  if (lane == 0) red[wave] = mx;
  __syncthreads();
  mx = fmaxf(fmaxf(red[0], red[1]), fmaxf(red[2], red[3]));
  __syncthreads();
  const float c = 1.4426950408889634f / 22.627416997969522f;  // log2(e)/sqrt(512)
  float p[8]; float sum = 0.f;
  #pragma unroll
  for (int j = 0; j < 8; ++j) { p[j] = exp2f((s[j] - mx) * c); sum += p[j]; }
  #pragma unroll
  for (int o = 32; o > 0; o >>= 1) sum += __shfl_xor(sum, o);
  if (lane == 0) red[wave] = sum;
  __syncthreads();
  sum = red[0] + red[1] + red[2] + red[3];
  float inv = 1.f / sum;
  u16x8 ov;
  #pragma unroll
  for (int j = 0; j < 8; ++j) ov[j] = f2bf(p[j] * inv);
  *(u16x8*)(row + tid*8) = ov;
}

__global__ __launch_bounds__(256) void pv_gemm(
    const unsigned short* __restrict__ sc, const unsigned short* __restrict__ vtb,
    float* __restrict__ out) {
  int bn = blockIdx.x, bm = blockIdx.y, b = blockIdx.z;
  __shared__ unsigned short As[2][LT], Bs[2][LT];
  int tid = threadIdx.x, wave = tid >> 6, lane = tid & 63;
  int wm = wave >> 1, wn = wave & 1;
  const unsigned short* A  = sc  + (long)b*S_*S_;   // P [2048][2048]
  const unsigned short* Bt = vtb + (long)b*D_*S_;   // V^T [512][2048]
  long rowA = (long)bm*128, rowB = (long)bn*128;
  f32x4 acc[4][4] = {};
  gemm_mainloop(A, S_, rowA, Bt, S_, rowB, 2*(bm+1), As, Bs, wave, lane, wm, wn, acc);
  float* oo = out + (long)b*S_*D_;
  int lr = (lane >> 4) * 4, lc = lane & 15;
  #pragma unroll
  for (int mt = 0; mt < 4; ++mt)
    #pragma unroll
    for (int nt = 0; nt < 4; ++nt)
      #pragma unroll
      for (int j = 0; j < 4; ++j) {
        long m = rowA + wm*64 + mt*16 + lr + j;
        long n = rowB + wn*64 + nt*16 + lc;
        oo[m*D_ + n] = acc[mt][nt][j];
      }
}

extern "C" void kernel_launch(void* const* d_in, const int* in_sizes, int n_in,
                              void* d_out, int out_size, void* d_ws, size_t ws_size,
                              hipStream_t stream) {
  const float* x   = (const float*)d_in[0];
  const float* wq  = (const float*)d_in[1];
  const float* bq  = (const float*)d_in[2];
  const float* wk  = (const float*)d_in[3];
  const float* bk  = (const float*)d_in[4];
  const float* wv  = (const float*)d_in[5];
  const float* bv  = (const float*)d_in[6];
  float* out = (float*)d_out;

  // workspace layout (bytes), total 87,031,808 (~83 MB)
  char* ws = (char*)d_ws;
  unsigned short* xb  = (unsigned short*)(ws);                 // 16,777,216  x bf16 [8192][1024]
  unsigned short* wbT = (unsigned short*)(ws + 16777216);      //  3,145,728  w^T bf16 [1536][1024]
  unsigned short* qb  = (unsigned short*)(ws + 19922944);      //  8,388,608  q bf16 [8192][512]
  unsigned short* kb  = (unsigned short*)(ws + 28311552);      //  8,388,608
  unsigned short* vb  = (unsigned short*)(ws + 36700160);      //  8,388,608
  unsigned short* vtb = (unsigned short*)(ws + 45088768);      //  8,388,608  v^T bf16 [4][512][2048]
  unsigned short* sc  = (unsigned short*)(ws + 53477376);      // 33,554,432  scores/P bf16 [4][2048][2048]

  convert_f32_bf16<<<dim3(4096), dim3(256), 0, stream>>>(x, xb);
  build_wT<<<dim3(6144), dim3(256), 0, stream>>>(wq, wk, wv, wbT);
  qkv_gemm<<<dim3(12, 64), dim3(256), 0, stream>>>(xb, wbT, bq, bk, bv, qb, kb, vb);
  transpose_v<<<dim3(8, 32, 4), dim3(256), 0, stream>>>(vb, vtb);
  scores_gemm<<<dim3(16, 16, 4), dim3(256), 0, stream>>>(qb, kb, sc);
  softmax_rows<<<dim3(2048, 4), dim3(256), 0, stream>>>(sc);
  pv_gemm<<<dim3(4, 16, 4), dim3(256), 0, stream>>>(sc, vtb, out);
}

// Round 2
// 160.325 us; speedup vs baseline: 1.0975x; 1.0975x over previous
//
#include <hip/hip_runtime.h>
#include <math.h>

// Self-attention: B=4, S=2048, E=1024, D=512, fp32 in/out, bf16 MFMA internally.
// Pipeline: convert -> fused QKV GEMM -> V transpose -> causal scores GEMM ->
//           row softmax (in-place P, zeros through diag block) -> causal PV GEMM.
// R2: GEMMs now 8 waves / 512 threads on 128x128 tile (2 blocks/CU -> 16 waves/CU
//     occupancy cap, was 8); softmax touches only cols <= diagonal block end.

typedef __attribute__((ext_vector_type(4))) float f32x4;
typedef __attribute__((ext_vector_type(8))) short bf16x8;     // 8 bf16 (4 VGPRs) MFMA frag
typedef __attribute__((ext_vector_type(8))) unsigned short u16x8;

#define B_ 4
#define S_ 2048
#define E_ 1024
#define D_ 512
#define LT (128*64)  // LDS tile: 128 rows x 64 bf16 (16 KB)

__device__ __forceinline__ unsigned short f2bf(float f) {
  unsigned u = __float_as_uint(f);
  u += 0x7fffu + ((u >> 16) & 1u);   // round-to-nearest-even
  return (unsigned short)(u >> 16);
}

__device__ __forceinline__ float bf2f(unsigned short h) {
  return __uint_as_float(((unsigned)h) << 16);
}

// ---- GEMM core: 128x128 tile, BK=64, 8 waves (2x4), 16x16x32 bf16 MFMA ----

__device__ __forceinline__ void stage_tile(const unsigned short* __restrict__ g, long ld,
                                           long rowBase, int kBase,
                                           unsigned short* lds, int tid) {
  // stage a 128x64 bf16 tile, linear LDS layout [row][64], via global_load_lds w16.
  // 512 threads x 16B = 8KB/iter; tile = 16KB -> 2 iters. LDS dest is
  // wave-uniform base + lane*16 (idx = i*512 + wave*64 + lane). Linear on both sides.
  #pragma unroll
  for (int i = 0; i < 2; ++i) {
    int idx = i*512 + tid;
    int row = idx >> 3, c8 = (idx & 7) * 8;
    __builtin_amdgcn_global_load_lds(
      (const __attribute__((address_space(1))) void*)(g + (rowBase + row)*ld + kBase + c8),
      (__attribute__((address_space(3))) void*)(lds + idx*8),
      16, 0, 0);
  }
}

__device__ __forceinline__ void compute_tile(const unsigned short* As, const unsigned short* Bs,
                                             int wm, int wn, int lane, f32x4 acc[4][2]) {
  // wave grid 2(m) x 4(n); per-wave output 64x32 of the 128x128 tile.
  int lm = lane & 15;
  int lk = (lane >> 4) * 8;
  #pragma unroll
  for (int kk = 0; kk < 2; ++kk) {
    bf16x8 af[4], bfr[2];
    #pragma unroll
    for (int mt = 0; mt < 4; ++mt)
      af[mt] = *(const bf16x8*)(As + (wm*64 + mt*16 + lm)*64 + kk*32 + lk);
    #pragma unroll
    for (int nt = 0; nt < 2; ++nt)
      bfr[nt] = *(const bf16x8*)(Bs + (wn*32 + nt*16 + lm)*64 + kk*32 + lk);
    #pragma unroll
    for (int mt = 0; mt < 4; ++mt)
      #pragma unroll
      for (int nt = 0; nt < 2; ++nt)
        acc[mt][nt] = __builtin_amdgcn_mfma_f32_16x16x32_bf16(af[mt], bfr[nt], acc[mt][nt], 0, 0, 0);
  }
}

__device__ __forceinline__ void gemm_mainloop(
    const unsigned short* __restrict__ A, long lda, long rowA,
    const unsigned short* __restrict__ Bt, long ldb, long rowB,
    int nsteps,
    unsigned short (*As)[LT], unsigned short (*Bs)[LT],
    int tid, int lane, int wm, int wn, f32x4 acc[4][2]) {
  // 2-phase double-buffered loop; __syncthreads drains vmcnt+lgkm.
  stage_tile(A, lda, rowA, 0, As[0], tid);
  stage_tile(Bt, ldb, rowB, 0, Bs[0], tid);
  __syncthreads();
  int cur = 0;
  for (int kt = 1; kt < nsteps; ++kt) {
    stage_tile(A, lda, rowA, kt*64, As[cur^1], tid);
    stage_tile(Bt, ldb, rowB, kt*64, Bs[cur^1], tid);
    compute_tile(As[cur], Bs[cur], wm, wn, lane, acc);
    __syncthreads();
    cur ^= 1;
  }
  compute_tile(As[cur], Bs[cur], wm, wn, lane, acc);
}

// ---- kernels ----

__global__ __launch_bounds__(256) void convert_f32_bf16(const float* __restrict__ src,
                                                        unsigned short* __restrict__ dst) {
  long i = (long)blockIdx.x*256 + threadIdx.x;  // 8 elems per thread
  f32x4 a = ((const f32x4*)src)[2*i];
  f32x4 b = ((const f32x4*)src)[2*i + 1];
  u16x8 o;
  #pragma unroll
  for (int j = 0; j < 4; ++j) { o[j] = f2bf(a[j]); o[4+j] = f2bf(b[j]); }
  ((u16x8*)dst)[i] = o;
}

// wbT[n][k] = w_sel[k][n&511], n in [0,1536). Column reads hit L2/L3 (6 MB total).
__global__ __launch_bounds__(256) void build_wT(const float* __restrict__ wq,
                                                const float* __restrict__ wk,
                                                const float* __restrict__ wv,
                                                unsigned short* __restrict__ wbT) {
  int o = blockIdx.x*256 + threadIdx.x;   // 1,572,864 total
  int n = o >> 10, k = o & 1023;
  const float* w = (n < 512) ? wq : ((n < 1024) ? wk : wv);
  int d = n & 511;
  wbT[o] = f2bf(w[(long)k*512 + d]);
}

__global__ __launch_bounds__(512) void qkv_gemm(
    const unsigned short* __restrict__ xb, const unsigned short* __restrict__ wbT,
    const float* __restrict__ bq, const float* __restrict__ bk, const float* __restrict__ bv,
    unsigned short* __restrict__ qb, unsigned short* __restrict__ kb,
    unsigned short* __restrict__ vb) {
  __shared__ unsigned short As[2][LT], Bs[2][LT];
  int tid = threadIdx.x, wave = tid >> 6, lane = tid & 63;
  int wm = wave >> 2, wn = wave & 3;
  long rowA = (long)blockIdx.y * 128;   // m block (8192/128 = 64)
  long rowB = (long)blockIdx.x * 128;   // n block (1536/128 = 12)
  f32x4 acc[4][2] = {};
  gemm_mainloop(xb, E_, rowA, wbT, E_, rowB, E_/64, As, Bs, tid, lane, wm, wn, acc);
  int lr = (lane >> 4) * 4, lc = lane & 15;
  #pragma unroll
  for (int nt = 0; nt < 2; ++nt) {
    int n = (int)rowB + wn*32 + nt*16 + lc;
    int d = n & 511;
    float bias; unsigned short* dst;
    if (n < 512)       { bias = bq[d]; dst = qb; }
    else if (n < 1024) { bias = bk[d]; dst = kb; }
    else               { bias = bv[d]; dst = vb; }
    #pragma unroll
    for (int mt = 0; mt < 4; ++mt) {
      #pragma unroll
      for (int j = 0; j < 4; ++j) {
        long m = rowA + wm*64 + mt*16 + lr + j;
        dst[m*D_ + d] = f2bf(acc[mt][nt][j] + bias);
      }
    }
  }
}

__global__ __launch_bounds__(256) void transpose_v(const unsigned short* __restrict__ vb,
                                                   unsigned short* __restrict__ vtb) {
  int dblk = blockIdx.x;   // 0..7
  int sblk = blockIdx.y;   // 0..31
  int b = blockIdx.z;
  __shared__ unsigned short ls[64][72];  // pad 8 keeps 16B alignment, breaks conflicts
  int tid = threadIdx.x;
  int r = tid >> 3, c8 = (tid & 7) * 8;
  long d0 = (long)dblk*64, s0 = (long)sblk*64;
  #pragma unroll
  for (int p = 0; p < 2; ++p) {
    u16x8 v = *(const u16x8*)(vb + ((long)b*S_ + s0 + r + p*32)*D_ + d0 + c8);
    *(u16x8*)&ls[r + p*32][c8] = v;
  }
  __syncthreads();
  #pragma unroll
  for (int p = 0; p < 2; ++p) {
    int d = r + p*32;
    u16x8 o;
    #pragma unroll
    for (int j = 0; j < 8; ++j) o[j] = ls[c8 + j][d];
    *(u16x8*)(vtb + ((long)b*D_ + d0 + d)*S_ + s0 + c8) = o;
  }
}

__global__ __launch_bounds__(512) void scores_gemm(
    const unsigned short* __restrict__ qb, const unsigned short* __restrict__ kb,
    unsigned short* __restrict__ sc) {
  int jb = blockIdx.x, ib = blockIdx.y, b = blockIdx.z;
  if (jb > ib) return;   // strictly-above-diagonal blocks never read downstream
  __shared__ unsigned short As[2][LT], Bs[2][LT];
  int tid = threadIdx.x, wave = tid >> 6, lane = tid & 63;
  int wm = wave >> 2, wn = wave & 3;
  const unsigned short* A  = qb + (long)b*S_*D_;
  const unsigned short* Bt = kb + (long)b*S_*D_;   // k stored [s][d] == [n][k]
  long rowA = (long)ib*128, rowB = (long)jb*128;
  f32x4 acc[4][2] = {};
  gemm_mainloop(A, D_, rowA, Bt, D_, rowB, D_/64, As, Bs, tid, lane, wm, wn, acc);
  unsigned short* so = sc + (long)b*S_*S_;
  int lr = (lane >> 4) * 4, lc = lane & 15;
  #pragma unroll
  for (int mt = 0; mt < 4; ++mt)
    #pragma unroll
    for (int nt = 0; nt < 2; ++nt)
      #pragma unroll
      for (int j = 0; j < 4; ++j) {
        long m = rowA + wm*64 + mt*16 + lr + j;
        long n = rowB + wn*32 + nt*16 + lc;
        so[m*S_ + n] = f2bf(acc[mt][nt][j]);   // raw score; scale+mask in softmax
      }
}

// one block per row; reads/writes bf16 P only on cols [0, diag-block-end);
// zeros above diag within the diagonal block -> PV never multiplies garbage,
// and PV's K-loop never reads past the diagonal block.
__global__ __launch_bounds__(256) void softmax_rows(unsigned short* __restrict__ sc) {
  int r = blockIdx.x, b = blockIdx.y;
  unsigned short* row = sc + ((long)b*S_ + r)*S_;
  int tid = threadIdx.x;
  int j0 = tid * 8;
  int limit = ((r >> 7) + 1) << 7;      // 128-aligned end of diagonal block
  bool act = (j0 < limit);
  u16x8 uv = {};
  if (act) uv = *(const u16x8*)(row + j0);
  float s[8];
  #pragma unroll
  for (int j = 0; j < 8; ++j) s[j] = (act && (j0 + j <= r)) ? bf2f(uv[j]) : -INFINITY;
  float mx = s[0];
  #pragma unroll
  for (int j = 1; j < 8; ++j) mx = fmaxf(mx, s[j]);
  #pragma unroll
  for (int o = 32; o > 0; o >>= 1) mx = fmaxf(mx, __shfl_xor(mx, o));
  __shared__ float red[4];
  int wave = tid >> 6, lane = tid & 63;
  if (lane == 0) red[wave] = mx;
  __syncthreads();
  mx = fmaxf(fmaxf(red[0], red[1]), fmaxf(red[2], red[3]));
  __syncthreads();
  const float c = 1.4426950408889634f / 22.627416997969522f;  // log2(e)/sqrt(512)
  float p[8]; float sum = 0.f;
  #pragma unroll
  for (int j = 0; j < 8; ++j) { p[j] = exp2f((s[j] - mx) * c); sum += p[j]; }
  #pragma unroll
  for (int o = 32; o > 0; o >>= 1) sum += __shfl_xor(sum, o);
  if (lane == 0) red[wave] = sum;
  __syncthreads();
  sum = red[0] + red[1] + red[2] + red[3];
  float inv = 1.f / sum;
  if (act) {
    u16x8 ov;
    #pragma unroll
    for (int j = 0; j < 8; ++j) ov[j] = f2bf(p[j] * inv);
    *(u16x8*)(row + j0) = ov;
  }
}

__global__ __launch_bounds__(512) void pv_gemm(
    const unsigned short* __restrict__ sc, const unsigned short* __restrict__ vtb,
    float* __restrict__ out) {
  int bn = blockIdx.x, bm = blockIdx.y, b = blockIdx.z;
  __shared__ unsigned short As[2][LT], Bs[2][LT];
  int tid = threadIdx.x, wave = tid >> 6, lane = tid & 63;
  int wm = wave >> 2, wn = wave & 3;
  const unsigned short* A  = sc  + (long)b*S_*S_;   // P [2048][2048]
  const unsigned short* Bt = vtb + (long)b*D_*S_;   // V^T [512][2048]
  long rowA = (long)bm*128, rowB = (long)bn*128;
  f32x4 acc[4][2] = {};
  gemm_mainloop(A, S_, rowA, Bt, S_, rowB, 2*(bm+1), As, Bs, tid, lane, wm, wn, acc);
  float* oo = out + (long)b*S_*D_;
  int lr = (lane >> 4) * 4, lc = lane & 15;
  #pragma unroll
  for (int mt = 0; mt < 4; ++mt)
    #pragma unroll
    for (int nt = 0; nt < 2; ++nt)
      #pragma unroll
      for (int j = 0; j < 4; ++j) {
        long m = rowA + wm*64 + mt*16 + lr + j;
        long n = rowB + wn*32 + nt*16 + lc;
        oo[m*D_ + n] = acc[mt][nt][j];
      }
}

extern "C" void kernel_launch(void* const* d_in, const int* in_sizes, int n_in,
                              void* d_out, int out_size, void* d_ws, size_t ws_size,
                              hipStream_t stream) {
  const float* x   = (const float*)d_in[0];
  const float* wq  = (const float*)d_in[1];
  const float* bq  = (const float*)d_in[2];
  const float* wk  = (const float*)d_in[3];
  const float* bk  = (const float*)d_in[4];
  const float* wv  = (const float*)d_in[5];
  const float* bv  = (const float*)d_in[6];
  float* out = (float*)d_out;

  // workspace layout (bytes), total 87,031,808 (~83 MB)
  char* ws = (char*)d_ws;
  unsigned short* xb  = (unsigned short*)(ws);                 // 16,777,216  x bf16 [8192][1024]
  unsigned short* wbT = (unsigned short*)(ws + 16777216);      //  3,145,728  w^T bf16 [1536][1024]
  unsigned short* qb  = (unsigned short*)(ws + 19922944);      //  8,388,608  q bf16 [8192][512]
  unsigned short* kb  = (unsigned short*)(ws + 28311552);      //  8,388,608
  unsigned short* vb  = (unsigned short*)(ws + 36700160);      //  8,388,608
  unsigned short* vtb = (unsigned short*)(ws + 45088768);      //  8,388,608  v^T bf16 [4][512][2048]
  unsigned short* sc  = (unsigned short*)(ws + 53477376);      // 33,554,432  scores/P bf16 [4][2048][2048]

  convert_f32_bf16<<<dim3(4096), dim3(256), 0, stream>>>(x, xb);
  build_wT<<<dim3(6144), dim3(256), 0, stream>>>(wq, wk, wv, wbT);
  qkv_gemm<<<dim3(12, 64), dim3(512), 0, stream>>>(xb, wbT, bq, bk, bv, qb, kb, vb);
  transpose_v<<<dim3(8, 32, 4), dim3(256), 0, stream>>>(vb, vtb);
  scores_gemm<<<dim3(16, 16, 4), dim3(512), 0, stream>>>(qb, kb, sc);
  softmax_rows<<<dim3(2048, 4), dim3(256), 0, stream>>>(sc);
  pv_gemm<<<dim3(4, 16, 4), dim3(512), 0, stream>>>(sc, vtb, out);
}

// Round 3
// 143.637 us; speedup vs baseline: 1.2250x; 1.1162x over previous
//
#include <hip/hip_runtime.h>
#include <math.h>

// Self-attention: B=4, S=2048, E=1024, D=512, fp32 in/out, bf16 MFMA internally.
// R3: all GEMMs moved to 32x32x16 MFMA, 4 waves/256 thr, BK=32 (32KB LDS ->
//     4 blocks/CU, qkv grid fully co-resident, no tail), XCD swizzle on qkv,
//     pv on 64-row tiles (512 blocks), softmax limit 64-aligned.

typedef __attribute__((ext_vector_type(4))) float f32x4;
typedef __attribute__((ext_vector_type(16))) float f32x16;
typedef __attribute__((ext_vector_type(8))) short bf16x8;     // 8 bf16 = 4 VGPRs
typedef __attribute__((ext_vector_type(8))) unsigned short u16x8;

#define B_ 4
#define S_ 2048
#define E_ 1024
#define D_ 512

__device__ __forceinline__ unsigned short f2bf(float f) {
  unsigned u = __float_as_uint(f);
  u += 0x7fffu + ((u >> 16) & 1u);   // round-to-nearest-even
  return (unsigned short)(u >> 16);
}

__device__ __forceinline__ float bf2f(unsigned short h) {
  return __uint_as_float(((unsigned)h) << 16);
}

// ---- GEMM core: BK=32, 32x32x16 bf16 MFMA, linear LDS [row][32] (64B rows) ----

template<int ROWS, int NTHR>
__device__ __forceinline__ void stage_tile32(const unsigned short* __restrict__ g, long ld,
                                             long rowBase, int kBase,
                                             unsigned short* lds, int tid) {
  // ROWS x 32 bf16 tile; 16B/thread/call; LDS dest linear = wave-uniform + lane*16. 
  constexpr int CALLS = (ROWS * 64) / (NTHR * 16);
  #pragma unroll
  for (int i = 0; i < CALLS; ++i) {
    int idx = i * NTHR + tid;
    int row = idx >> 2, c8 = (idx & 3) * 8;
    __builtin_amdgcn_global_load_lds(
      (const __attribute__((address_space(1))) void*)(g + (rowBase + row) * ld + kBase + c8),
      (__attribute__((address_space(3))) void*)(lds + idx * 8),
      16, 0, 0);
  }
}

// A frag for 32x32x16: lane reads A[row = lane&31][k = (lane>>5)*8 + 0..7]; B mirrors.
template<int MT, int NTT>
__device__ __forceinline__ void compute_tile32(const unsigned short* As, const unsigned short* Bs,
                                               int a_row0, int b_row0, int lane,
                                               f32x16 (&acc)[MT][NTT]) {
  int lr = lane & 31, lk = (lane >> 5) * 8;
  #pragma unroll
  for (int ki = 0; ki < 2; ++ki) {
    bf16x8 af[MT], bf[NTT];
    #pragma unroll
    for (int mt = 0; mt < MT; ++mt)
      af[mt] = *(const bf16x8*)(As + (a_row0 + mt * 32 + lr) * 32 + ki * 16 + lk);
    #pragma unroll
    for (int nt = 0; nt < NTT; ++nt)
      bf[nt] = *(const bf16x8*)(Bs + (b_row0 + nt * 32 + lr) * 32 + ki * 16 + lk);
    #pragma unroll
    for (int mt = 0; mt < MT; ++mt)
      #pragma unroll
      for (int nt = 0; nt < NTT; ++nt)
        acc[mt][nt] = __builtin_amdgcn_mfma_f32_32x32x16_bf16(af[mt], bf[nt], acc[mt][nt], 0, 0, 0);
  }
}

template<int AROWS, int BROWS, int NTHR, int MT, int NTT>
__device__ __forceinline__ void mainloop32(
    const unsigned short* __restrict__ A, long lda, long rowA,
    const unsigned short* __restrict__ Bt, long ldb, long rowB,
    int nsteps, unsigned short* AsBuf, unsigned short* BsBuf,
    int tid, int lane, int a_row0, int b_row0, f32x16 (&acc)[MT][NTT]) {
  constexpr int ASZ = AROWS * 32, BSZ = BROWS * 32;
  stage_tile32<AROWS, NTHR>(A, lda, rowA, 0, AsBuf, tid);
  stage_tile32<BROWS, NTHR>(Bt, ldb, rowB, 0, BsBuf, tid);
  __syncthreads();
  int cur = 0;
  for (int kt = 1; kt < nsteps; ++kt) {
    stage_tile32<AROWS, NTHR>(A, lda, rowA, kt * 32, AsBuf + (cur ^ 1) * ASZ, tid);
    stage_tile32<BROWS, NTHR>(Bt, ldb, rowB, kt * 32, BsBuf + (cur ^ 1) * BSZ, tid);
    compute_tile32<MT, NTT>(AsBuf + cur * ASZ, BsBuf + cur * BSZ, a_row0, b_row0, lane, acc);
    __syncthreads();
    cur ^= 1;
  }
  compute_tile32<MT, NTT>(AsBuf + cur * ASZ, BsBuf + cur * BSZ, a_row0, b_row0, lane, acc);
}

// ---- kernels ----

__global__ __launch_bounds__(256) void convert_f32_bf16(const float* __restrict__ src,
                                                        unsigned short* __restrict__ dst) {
  long i = (long)blockIdx.x * 256 + threadIdx.x;  // 8 elems per thread
  f32x4 a = ((const f32x4*)src)[2 * i];
  f32x4 b = ((const f32x4*)src)[2 * i + 1];
  u16x8 o;
  #pragma unroll
  for (int j = 0; j < 4; ++j) { o[j] = f2bf(a[j]); o[4 + j] = f2bf(b[j]); }
  ((u16x8*)dst)[i] = o;
}

// wbT[n][k] = w_sel[k][n&511], n in [0,1536). Column reads hit L2/L3 (6 MB total).
__global__ __launch_bounds__(256) void build_wT(const float* __restrict__ wq,
                                                const float* __restrict__ wk,
                                                const float* __restrict__ wv,
                                                unsigned short* __restrict__ wbT) {
  int o = blockIdx.x * 256 + threadIdx.x;   // 1,572,864 total
  int n = o >> 10, k = o & 1023;
  const float* w = (n < 512) ? wq : ((n < 1024) ? wk : wv);
  int d = n & 511;
  wbT[o] = f2bf(w[(long)k * 512 + d]);
}

__global__ __launch_bounds__(256, 4) void qkv_gemm(
    const unsigned short* __restrict__ xb, const unsigned short* __restrict__ wbT,
    const float* __restrict__ bq, const float* __restrict__ bk, const float* __restrict__ bv,
    unsigned short* __restrict__ qb, unsigned short* __restrict__ kb,
    unsigned short* __restrict__ vb) {
  __shared__ unsigned short As[2][128 * 32], Bs[2][128 * 32];   // 32 KB
  int tid = threadIdx.x, wave = tid >> 6, lane = tid & 63;
  int wm = wave >> 1, wn = wave & 1;
  // XCD-aware bijective swizzle: 768 wgs, 96 per XCD chunk (768 % 8 == 0).
  int wg = blockIdx.x;
  int swz = (wg & 7) * 96 + (wg >> 3);
  int nb = swz % 12, mb = swz / 12;                // n fastest -> chunk shares A panel
  long rowA = (long)mb * 128, rowB = (long)nb * 128;
  f32x16 acc[2][2] = {};
  mainloop32<128, 128, 256, 2, 2>(xb, E_, rowA, wbT, E_, rowB, E_ / 32,
                                  &As[0][0], &Bs[0][0], tid, lane, wm * 64, wn * 64, acc);
  int lc = lane & 31, lhi = (lane >> 5) * 4;
  #pragma unroll
  for (int nt = 0; nt < 2; ++nt) {
    int n = (int)rowB + wn * 64 + nt * 32 + lc;
    int d = n & 511;
    float bias; unsigned short* dst;
    if (n < 512)       { bias = bq[d]; dst = qb; }
    else if (n < 1024) { bias = bk[d]; dst = kb; }
    else               { bias = bv[d]; dst = vb; }
    #pragma unroll
    for (int mt = 0; mt < 2; ++mt) {
      long mbase = rowA + wm * 64 + mt * 32 + lhi;
      #pragma unroll
      for (int r = 0; r < 16; ++r) {
        long m = mbase + (r & 3) + 8 * (r >> 2);
        dst[m * D_ + d] = f2bf(acc[mt][nt][r] + bias);
      }
    }
  }
}

__global__ __launch_bounds__(256) void transpose_v(const unsigned short* __restrict__ vb,
                                                   unsigned short* __restrict__ vtb) {
  int dblk = blockIdx.x;   // 0..7
  int sblk = blockIdx.y;   // 0..31
  int b = blockIdx.z;
  __shared__ unsigned short ls[64][72];  // pad 8 keeps 16B alignment, breaks conflicts
  int tid = threadIdx.x;
  int r = tid >> 3, c8 = (tid & 7) * 8;
  long d0 = (long)dblk * 64, s0 = (long)sblk * 64;
  #pragma unroll
  for (int p = 0; p < 2; ++p) {
    u16x8 v = *(const u16x8*)(vb + ((long)b * S_ + s0 + r + p * 32) * D_ + d0 + c8);
    *(u16x8*)&ls[r + p * 32][c8] = v;
  }
  __syncthreads();
  #pragma unroll
  for (int p = 0; p < 2; ++p) {
    int d = r + p * 32;
    u16x8 o;
    #pragma unroll
    for (int j = 0; j < 8; ++j) o[j] = ls[c8 + j][d];
    *(u16x8*)(vtb + ((long)b * D_ + d0 + d) * S_ + s0 + c8) = o;
  }
}

__global__ __launch_bounds__(256, 4) void scores_gemm(
    const unsigned short* __restrict__ qb, const unsigned short* __restrict__ kb,
    unsigned short* __restrict__ sc) {
  int jb = blockIdx.x, ib = blockIdx.y, b = blockIdx.z;
  if (jb > ib) return;   // strictly-above-diagonal blocks never read downstream
  __shared__ unsigned short As[2][128 * 32], Bs[2][128 * 32];
  int tid = threadIdx.x, wave = tid >> 6, lane = tid & 63;
  int wm = wave >> 1, wn = wave & 1;
  const unsigned short* A  = qb + (long)b * S_ * D_;
  const unsigned short* Bt = kb + (long)b * S_ * D_;   // k stored [s][d] == [n][k]
  long rowA = (long)ib * 128, rowB = (long)jb * 128;
  f32x16 acc[2][2] = {};
  mainloop32<128, 128, 256, 2, 2>(A, D_, rowA, Bt, D_, rowB, D_ / 32,
                                  &As[0][0], &Bs[0][0], tid, lane, wm * 64, wn * 64, acc);
  unsigned short* so = sc + (long)b * S_ * S_;
  int lc = lane & 31, lhi = (lane >> 5) * 4;
  #pragma unroll
  for (int mt = 0; mt < 2; ++mt) {
    long mbase = rowA + wm * 64 + mt * 32 + lhi;
    #pragma unroll
    for (int nt = 0; nt < 2; ++nt) {
      long n = rowB + wn * 64 + nt * 32 + lc;
      #pragma unroll
      for (int r = 0; r < 16; ++r) {
        long m = mbase + (r & 3) + 8 * (r >> 2);
        so[m * S_ + n] = f2bf(acc[mt][nt][r]);   // raw score; scale+mask in softmax
      }
    }
  }
}

// one block per row; touches bf16 P only on cols [0, 64-aligned diag end);
// zeros above diag within that range -> PV K-loop (64-granular) reads exact data.
__global__ __launch_bounds__(256) void softmax_rows(unsigned short* __restrict__ sc) {
  int r = blockIdx.x, b = blockIdx.y;
  unsigned short* row = sc + ((long)b * S_ + r) * S_;
  int tid = threadIdx.x;
  int j0 = tid * 8;
  int limit = ((r >> 6) + 1) << 6;      // 64-aligned end of diagonal block
  bool act = (j0 < limit);
  u16x8 uv = {};
  if (act) uv = *(const u16x8*)(row + j0);
  float s[8];
  #pragma unroll
  for (int j = 0; j < 8; ++j) s[j] = (act && (j0 + j <= r)) ? bf2f(uv[j]) : -INFINITY;
  float mx = s[0];
  #pragma unroll
  for (int j = 1; j < 8; ++j) mx = fmaxf(mx, s[j]);
  #pragma unroll
  for (int o = 32; o > 0; o >>= 1) mx = fmaxf(mx, __shfl_xor(mx, o));
  __shared__ float red[4];
  int wave = tid >> 6, lane = tid & 63;
  if (lane == 0) red[wave] = mx;
  __syncthreads();
  mx = fmaxf(fmaxf(red[0], red[1]), fmaxf(red[2], red[3]));
  __syncthreads();
  const float c = 1.4426950408889634f / 22.627416997969522f;  // log2(e)/sqrt(512)
  float p[8]; float sum = 0.f;
  #pragma unroll
  for (int j = 0; j < 8; ++j) { p[j] = exp2f((s[j] - mx) * c); sum += p[j]; }
  #pragma unroll
  for (int o = 32; o > 0; o >>= 1) sum += __shfl_xor(sum, o);
  if (lane == 0) red[wave] = sum;
  __syncthreads();
  sum = red[0] + red[1] + red[2] + red[3];
  float inv = 1.f / sum;
  if (act) {
    u16x8 ov;
    #pragma unroll
    for (int j = 0; j < 8; ++j) ov[j] = f2bf(p[j] * inv);
    *(u16x8*)(row + j0) = ov;
  }
}

__global__ __launch_bounds__(256, 4) void pv_gemm(
    const unsigned short* __restrict__ sc, const unsigned short* __restrict__ vtb,
    float* __restrict__ out) {
  int bn = blockIdx.x;   // 0..3   (128-col slice of D)
  int bm = blockIdx.y;   // 0..31  (64-row slice of S)
  int b  = blockIdx.z;
  __shared__ unsigned short As[2][64 * 32], Bs[2][128 * 32];   // 24 KB
  int tid = threadIdx.x, wave = tid >> 6, lane = tid & 63;
  int wm = wave >> 1, wn = wave & 1;   // per-wave 32(m) x 64(n)
  const unsigned short* A  = sc  + (long)b * S_ * S_;   // P [2048][2048]
  const unsigned short* Bt = vtb + (long)b * D_ * S_;   // V^T [512][2048]
  long rowA = (long)bm * 64, rowB = (long)bn * 128;
  f32x16 acc[1][2] = {};
  mainloop32<64, 128, 256, 1, 2>(A, S_, rowA, Bt, S_, rowB, 2 * (bm + 1),
                                 &As[0][0], &Bs[0][0], tid, lane, wm * 32, wn * 64, acc);
  float* oo = out + (long)b * S_ * D_;
  int lc = lane & 31, lhi = (lane >> 5) * 4;
  long mbase = rowA + wm * 32 + lhi;
  #pragma unroll
  for (int nt = 0; nt < 2; ++nt) {
    long n = rowB + wn * 64 + nt * 32 + lc;
    #pragma unroll
    for (int r = 0; r < 16; ++r) {
      long m = mbase + (r & 3) + 8 * (r >> 2);
      oo[m * D_ + n] = acc[0][nt][r];
    }
  }
}

extern "C" void kernel_launch(void* const* d_in, const int* in_sizes, int n_in,
                              void* d_out, int out_size, void* d_ws, size_t ws_size,
                              hipStream_t stream) {
  const float* x   = (const float*)d_in[0];
  const float* wq  = (const float*)d_in[1];
  const float* bq  = (const float*)d_in[2];
  const float* wk  = (const float*)d_in[3];
  const float* bk  = (const float*)d_in[4];
  const float* wv  = (const float*)d_in[5];
  const float* bv  = (const float*)d_in[6];
  float* out = (float*)d_out;

  // workspace layout (bytes), total 87,031,808 (~83 MB)
  char* ws = (char*)d_ws;
  unsigned short* xb  = (unsigned short*)(ws);                 // 16,777,216  x bf16 [8192][1024]
  unsigned short* wbT = (unsigned short*)(ws + 16777216);      //  3,145,728  w^T bf16 [1536][1024]
  unsigned short* qb  = (unsigned short*)(ws + 19922944);      //  8,388,608  q bf16 [8192][512]
  unsigned short* kb  = (unsigned short*)(ws + 28311552);      //  8,388,608
  unsigned short* vb  = (unsigned short*)(ws + 36700160);      //  8,388,608
  unsigned short* vtb = (unsigned short*)(ws + 45088768);      //  8,388,608  v^T bf16 [4][512][2048]
  unsigned short* sc  = (unsigned short*)(ws + 53477376);      // 33,554,432  scores/P bf16 [4][2048][2048]

  convert_f32_bf16<<<dim3(4096), dim3(256), 0, stream>>>(x, xb);
  build_wT<<<dim3(6144), dim3(256), 0, stream>>>(wq, wk, wv, wbT);
  qkv_gemm<<<dim3(768), dim3(256), 0, stream>>>(xb, wbT, bq, bk, bv, qb, kb, vb);
  transpose_v<<<dim3(8, 32, 4), dim3(256), 0, stream>>>(vb, vtb);
  scores_gemm<<<dim3(16, 16, 4), dim3(256), 0, stream>>>(qb, kb, sc);
  softmax_rows<<<dim3(2048, 4), dim3(256), 0, stream>>>(sc);
  pv_gemm<<<dim3(4, 32, 4), dim3(256), 0, stream>>>(sc, vtb, out);
}